// Round 4
// baseline (296.269 us; speedup 1.0000x reference)
//
#include <hip/hip_runtime.h>
#include <stdint.h>

// Problem constants
#define BATCH 8
#define TT    2048
#define CC    1024
#define GG    2
#define EE    320
#define KN    (GG * EE)    // 640
#define DD    256
#define MTOT  (BATCH * TT) // 16384
#define WK2   2048         // B2 row stride (shorts): [hi(0:1024) | lo(1024:2048)]

typedef __attribute__((ext_vector_type(8))) short short8;
typedef __attribute__((ext_vector_type(4))) float f32x4;

__device__ __forceinline__ unsigned int f32_orderable(float x) {
    unsigned int b = __float_as_uint(x);
    return (b & 0x80000000u) ? ~b : (b | 0x80000000u);
}

__device__ __forceinline__ unsigned short bf16_rne(float x) {
    unsigned int u = __float_as_uint(x);
    return (unsigned short)((u + 0x7FFFu + ((u >> 16) & 1u)) >> 16);
}

__global__ void init_slots_kernel(unsigned long long* __restrict__ slots) {
    if (threadIdx.x < 16) slots[threadIdx.x] = 0ull;
}

// fp32 (rows x 1024) -> bf16 hi/lo split, row-major rows x 2048: [hi | lo].
// Used for W only now. init_slots=1 also zeroes the 16 argmax slots.
__global__ __launch_bounds__(256)
void convert_split_kernel(const float* __restrict__ src, unsigned short* __restrict__ dst,
                          int n_i4, unsigned long long* __restrict__ slots, int init_slots) {
    int i4 = blockIdx.x * blockDim.x + threadIdx.x;
    if (init_slots && blockIdx.x == 0 && threadIdx.x < 16) slots[threadIdx.x] = 0ull;
    if (i4 >= n_i4) return;
    int m = i4 >> 8;
    int k = (i4 & 255) * 4;
    float4 v = ((const float4*)src)[i4];
    ushort4 hi, lo;
    hi.x = bf16_rne(v.x); lo.x = bf16_rne(v.x - __uint_as_float((unsigned)hi.x << 16));
    hi.y = bf16_rne(v.y); lo.y = bf16_rne(v.y - __uint_as_float((unsigned)hi.y << 16));
    hi.z = bf16_rne(v.z); lo.z = bf16_rne(v.z - __uint_as_float((unsigned)hi.z << 16));
    hi.w = bf16_rne(v.w); lo.w = bf16_rne(v.w - __uint_as_float((unsigned)hi.w << 16));
    *(ushort4*)(dst + (size_t)m * WK2 + k)        = hi;
    *(ushort4*)(dst + (size_t)m * WK2 + 1024 + k) = lo;
}

__device__ __forceinline__ void gload_lds16(const void* g, void* l) {
    __builtin_amdgcn_global_load_lds(
        (const __attribute__((address_space(1))) unsigned int*)g,
        (__attribute__((address_space(3))) unsigned int*)l,
        16, 0, 0);
}

// 8 fp32 -> bf16 hi (round-half-up; carry into exponent is correct) and
// lo = bf16-trunc-ish of the EXACT residual x - upcast(hi). Total error ~2^-17|x|.
__device__ __forceinline__ void cvt_hilo8(float4 a, float4 b, short8& hi, short8& lo) {
    float x[8] = {a.x, a.y, a.z, a.w, b.x, b.y, b.z, b.w};
#pragma unroll
    for (int j = 0; j < 8; j++) {
        unsigned int u  = __float_as_uint(x[j]);
        unsigned int v  = u + 0x8000u;
        float hif       = __uint_as_float(v & 0xFFFF0000u);
        float lof       = x[j] - hif;                 // exact in fp32
        unsigned int lu = __float_as_uint(lof) + 0x8000u;
        hi[j] = (short)(v >> 16);
        lo[j] = (short)(lu >> 16);
    }
}

// ------------------- MFMA path -------------------
// C = X * W^T via split-bf16 (ah*bh + al*bh + ah*bl), A converted IN-REGISTER
// from fp32 X (no A LDS), B staged via global_load_lds into double-buffered,
// bank-swizzled LDS. One barrier per K-iter; next-iter loads stay in flight
// across the compute phase. Consumed only by per-(m/1024) packed argmax.
__global__ __launch_bounds__(256)
void gemm_argmax_mfma(const float* __restrict__ X,
                      const unsigned short* __restrict__ B2,
                      const float* __restrict__ bias,
                      unsigned long long* __restrict__ slots) {
    // Bs[buf][hi/lo]: 128 rows x 32 shorts (64B/row), source-column-rotated
    __shared__ unsigned short Bs[2][2][128 * 32];   // 32 KB
    __shared__ unsigned long long red[4];

    const int tid  = threadIdx.x;
    const int lane = tid & 63;
    const int wave = tid >> 6;

    // XCD swizzle: one XCD covers 16 m-tiles x all 5 n-tiles (n fastest).
    const int l   = blockIdx.x;        // 0..639
    const int xcd = l & 7;
    const int w   = l >> 3;
    const int mt  = xcd * 16 + w / 5;
    const int nt  = w % 5;
    const int m0 = mt * 128;
    const int n0 = nt * 128;

    const int wm = (wave >> 1) * 64;
    const int wn = (wave & 1) * 64;

    const int fr  = lane & 15;
    const int q   = lane >> 4;
    const int fk8 = q * 8;

    // A fragment base pointers: lane (fr,q) holds A[row][q*8..q*8+8) — the
    // exact 16x16x32 A-operand layout, loaded as 2x float4 fp32 per tile.
    const float* Ap[4];
#pragma unroll
    for (int t = 0; t < 4; t++)
        Ap[t] = X + (size_t)(m0 + wm + t * 16 + fr) * CC + fk8;

    // B staging: per wave 2 chunks of 16 rows; lane -> (row, dest-slot lane&3).
    // Source column slot rotated by (rowInTile>>1) so frag reads are conflict-free.
    int soff[2];
#pragma unroll
    for (int c = 0; c < 2; c++) {
        int rt   = wave * 32 + c * 16 + (lane >> 2);       // row in tile
        int slot = ((lane & 3) - (rt >> 1)) & 3;
        soff[c]  = (n0 + rt) * WK2 + slot * 8;             // shorts
    }
    const int ldsb0 = (wave * 32) * 64;                    // byte offsets (wave-uniform)
    const int ldsb1 = (wave * 32 + 16) * 64;

    // Fragment read offset (shorts): row (wn+fr), rotated column slot
    const int fbase = (wn + fr) * 32 + ((q + (fr >> 1)) & 3) * 8;

    f32x4 acc[4][4] = {};
    float4 Ar[8];
    short8 ahc[4], alc[4];

    // ---- prologue: stage B(buf0,k=0), load+convert A(k=0) ----
#pragma unroll
    for (int c = 0; c < 2; c++) {
        const unsigned short* sp = B2 + soff[c];
        int lb = c ? ldsb1 : ldsb0;
        gload_lds16(sp,        (char*)Bs[0][0] + lb);
        gload_lds16(sp + 1024, (char*)Bs[0][1] + lb);
    }
#pragma unroll
    for (int t = 0; t < 4; t++) {
        Ar[2 * t]     = *(const float4*)(Ap[t]);
        Ar[2 * t + 1] = *(const float4*)(Ap[t] + 4);
    }
#pragma unroll
    for (int t = 0; t < 4; t++) cvt_hilo8(Ar[2 * t], Ar[2 * t + 1], ahc[t], alc[t]);

#define HALFSTEP(BUF, K0, KN_, HASNEXT)                                          \
    {                                                                            \
        __syncthreads(); /* buf BUF staged (vmcnt drain had full compute phase)*/\
        if (HASNEXT) {                                                           \
            _Pragma("unroll")                                                    \
            for (int c = 0; c < 2; c++) {                                        \
                const unsigned short* sp = B2 + soff[c] + (KN_);                 \
                int lb = c ? ldsb1 : ldsb0;                                      \
                gload_lds16(sp,        (char*)Bs[(BUF) ^ 1][0] + lb);            \
                gload_lds16(sp + 1024, (char*)Bs[(BUF) ^ 1][1] + lb);            \
            }                                                                    \
            _Pragma("unroll")                                                    \
            for (int t = 0; t < 4; t++) {                                        \
                Ar[2 * t]     = *(const float4*)(Ap[t] + (KN_));                 \
                Ar[2 * t + 1] = *(const float4*)(Ap[t] + (KN_) + 4);             \
            }                                                                    \
        }                                                                        \
        short8 bh[4], bl[4];                                                     \
        _Pragma("unroll")                                                        \
        for (int t = 0; t < 4; t++) {                                            \
            bh[t] = *(const short8*)&Bs[BUF][0][fbase + t * 512];                \
            bl[t] = *(const short8*)&Bs[BUF][1][fbase + t * 512];                \
        }                                                                        \
        _Pragma("unroll")                                                        \
        for (int ti = 0; ti < 4; ti++)                                           \
            _Pragma("unroll")                                                    \
            for (int tj = 0; tj < 4; tj++)                                       \
                acc[ti][tj] = __builtin_amdgcn_mfma_f32_16x16x32_bf16(           \
                    ahc[ti], bh[tj], acc[ti][tj], 0, 0, 0);                      \
        _Pragma("unroll")                                                        \
        for (int ti = 0; ti < 4; ti++)                                           \
            _Pragma("unroll")                                                    \
            for (int tj = 0; tj < 4; tj++)                                       \
                acc[ti][tj] = __builtin_amdgcn_mfma_f32_16x16x32_bf16(           \
                    alc[ti], bh[tj], acc[ti][tj], 0, 0, 0);                      \
        _Pragma("unroll")                                                        \
        for (int ti = 0; ti < 4; ti++)                                           \
            _Pragma("unroll")                                                    \
            for (int tj = 0; tj < 4; tj++)                                       \
                acc[ti][tj] = __builtin_amdgcn_mfma_f32_16x16x32_bf16(           \
                    ahc[ti], bl[tj], acc[ti][tj], 0, 0, 0);                      \
        if (HASNEXT) {                                                           \
            _Pragma("unroll")                                                    \
            for (int t = 0; t < 4; t++)                                          \
                cvt_hilo8(Ar[2 * t], Ar[2 * t + 1], ahc[t], alc[t]);             \
        }                                                                        \
    }

    for (int it = 0; it < 16; it++) {
        int k0 = it * 64;
        HALFSTEP(0, k0, k0 + 32, 1)
        HALFSTEP(1, k0 + 32, k0 + 64, (it < 15))
    }
#undef HALFSTEP

    // ---- fused argmax epilogue ----
    // C/D layout (16x16x32): col = lane&15, row = (lane>>4)*4 + reg
    float bias4[4];
#pragma unroll
    for (int tj = 0; tj < 4; tj++) bias4[tj] = bias[n0 + wn + tj * 16 + (lane & 15)];

    unsigned long long best = 0ull;
#pragma unroll
    for (int ti = 0; ti < 4; ti++) {
#pragma unroll
        for (int r = 0; r < 4; r++) {
            int m  = m0 + wm + ti * 16 + (lane >> 4) * 4 + r;
            int tl = m & 1023;
#pragma unroll
            for (int tj = 0; tj < 4; tj++) {
                int n = n0 + wn + tj * 16 + (lane & 15);
                float v = acc[ti][tj][r] + bias4[tj];
                unsigned int c = (unsigned int)(tl * KN + n);
                unsigned long long p =
                    ((unsigned long long)f32_orderable(v) << 32) |
                    (unsigned long long)(~c);
                if (p > best) best = p;
            }
        }
    }
#pragma unroll
    for (int off = 32; off > 0; off >>= 1) {
        unsigned long long o = __shfl_down(best, off, 64);
        if (o > best) best = o;
    }
    if (lane == 0) red[wave] = best;
    __syncthreads();
    if (tid == 0) {
        unsigned long long b = red[0];
        for (int wv = 1; wv < 4; wv++) if (red[wv] > b) b = red[wv];
        atomicMax(slots + (m0 >> 10), b);
    }
}

// ------------------- fused zero + scatter -------------------
// Writes the ENTIRE output: zeros everywhere except the 16 selected rows,
// which get their group's codebook row. One launch instead of two.
__global__ __launch_bounds__(256)
void zs_kernel(const unsigned long long* __restrict__ slots,
               const float* __restrict__ codebook,
               float4* __restrict__ out4) {
    int i4 = blockIdx.x * 256 + threadIdx.x;       // 2,097,152 float4s
    int n  = i4 >> 7;                              // output row (0..16383)
    int c4 = i4 & 127;                             // float4 within 512-float row
    int b  = n >> 11;
    int h  = (n >> 10) & 1;
    unsigned long long p = slots[b * 2 + h];
    unsigned int c = ~(unsigned int)(p & 0xFFFFFFFFull);
    int tl = (int)(c / KN);
    int kg = (int)(c % KN);
    int nstar = b * 2048 + h * 1024 + tl;
    int g = kg / EE;                               // group 0/1 -> half of the 512 row
    float4 v = make_float4(0.f, 0.f, 0.f, 0.f);
    if (n == nstar && (c4 >> 6) == g)
        v = ((const float4*)codebook)[kg * 64 + (c4 & 63)];
    out4[i4] = v;
}

// ------------------- fp32 fallback path (used only if ws too small) -------------------
#define BM 128
#define BN 64
#define BK 32
#define LDA (BM + 4)
#define LDB (BN + 4)

__global__ __launch_bounds__(128)
void gemm_argmax_f32(const float* __restrict__ X, const float* __restrict__ W,
                     const float* __restrict__ bias,
                     unsigned long long* __restrict__ slots) {
    __shared__ float As[BK][LDA];
    __shared__ float Bs[BK][LDB];
    const int tid = threadIdx.x;
    const int m0 = blockIdx.y * BM;
    const int n0 = blockIdx.x * BN;
    const int tx = tid & 7, ty = tid >> 3;
    float acc[8][8];
#pragma unroll
    for (int i = 0; i < 8; i++)
#pragma unroll
        for (int j = 0; j < 8; j++) acc[i][j] = 0.0f;
    const int lm = tid >> 3, lk = (tid & 7) * 4;
    const float* Xb = X + (size_t)m0 * CC;
    const float* Wb = W + (size_t)n0 * CC;
    for (int k0 = 0; k0 < CC; k0 += BK) {
#pragma unroll
        for (int r = 0; r < 8; r++) {
            int m = r * 16 + lm;
            float4 v = *(const float4*)(Xb + (size_t)m * CC + k0 + lk);
            As[lk + 0][m] = v.x; As[lk + 1][m] = v.y; As[lk + 2][m] = v.z; As[lk + 3][m] = v.w;
        }
#pragma unroll
        for (int r = 0; r < 4; r++) {
            int m = r * 16 + lm;
            float4 v = *(const float4*)(Wb + (size_t)m * CC + k0 + lk);
            Bs[lk + 0][m] = v.x; Bs[lk + 1][m] = v.y; Bs[lk + 2][m] = v.z; Bs[lk + 3][m] = v.w;
        }
        __syncthreads();
#pragma unroll
        for (int kk = 0; kk < BK; kk++) {
            float4 a0 = *(const float4*)&As[kk][ty * 8];
            float4 a1 = *(const float4*)&As[kk][ty * 8 + 4];
            float4 b0 = *(const float4*)&Bs[kk][tx * 8];
            float4 b1 = *(const float4*)&Bs[kk][tx * 8 + 4];
            float a[8] = {a0.x, a0.y, a0.z, a0.w, a1.x, a1.y, a1.z, a1.w};
            float b[8] = {b0.x, b0.y, b0.z, b0.w, b1.x, b1.y, b1.z, b1.w};
#pragma unroll
            for (int i = 0; i < 8; i++)
#pragma unroll
                for (int j = 0; j < 8; j++) acc[i][j] = fmaf(a[i], b[j], acc[i][j]);
        }
        __syncthreads();
    }
    unsigned long long best = 0ull;
#pragma unroll
    for (int i = 0; i < 8; i++) {
        int mg = m0 + ty * 8 + i;
        int tl = mg & 1023;
#pragma unroll
        for (int j = 0; j < 8; j++) {
            int kg = n0 + tx * 8 + j;
            float v = acc[i][j] + bias[kg];
            unsigned int c = (unsigned int)(tl * KN + kg);
            unsigned long long p = ((unsigned long long)f32_orderable(v) << 32) |
                                   (unsigned long long)(~c);
            if (p > best) best = p;
        }
    }
#pragma unroll
    for (int off = 32; off > 0; off >>= 1) {
        unsigned long long o = __shfl_down(best, off, 64);
        if (o > best) best = o;
    }
    __shared__ unsigned long long red2[2];
    if ((tid & 63) == 0) red2[tid >> 6] = best;
    __syncthreads();
    if (tid == 0) {
        unsigned long long b0 = red2[0], b1 = red2[1];
        atomicMax(slots + (m0 >> 10), b0 > b1 ? b0 : b1);
    }
}

extern "C" void kernel_launch(void* const* d_in, const int* in_sizes, int n_in,
                              void* d_out, int out_size, void* d_ws, size_t ws_size,
                              hipStream_t stream) {
    const float* X        = (const float*)d_in[0];  // (8,2048,1024)
    const float* W        = (const float*)d_in[1];  // (640,1024)
    const float* bias     = (const float*)d_in[2];  // (640,)
    const float* codebook = (const float*)d_in[3];  // (640,256)
    float* out = (float*)d_out;                     // (8,2048,512) fp32

    unsigned long long* slots = (unsigned long long*)d_ws;
    const size_t B2_off = 256;
    const size_t B2_bytes = (size_t)KN * WK2 * 2;        // 2,621,440
    const size_t need = B2_off + B2_bytes;

    if (ws_size >= need) {
        unsigned short* B2 = (unsigned short*)((char*)d_ws + B2_off);
        int nw = KN * CC / 4;     // 163,840 -> 640 blocks
        hipLaunchKernelGGL(convert_split_kernel, dim3(nw / 256), dim3(256), 0, stream,
                           W, B2, nw, slots, 1);
        hipLaunchKernelGGL(gemm_argmax_mfma, dim3(640), dim3(256), 0, stream,
                           X, B2, bias, slots);
    } else {
        hipLaunchKernelGGL(init_slots_kernel, dim3(1), dim3(64), 0, stream, slots);
        hipLaunchKernelGGL(gemm_argmax_f32, dim3(KN / BN, MTOT / BM), dim3(128), 0, stream,
                           X, W, bias, slots);
    }

    int n4 = out_size / 4;        // 2,097,152
    hipLaunchKernelGGL(zs_kernel, dim3(n4 / 256), dim3(256), 0, stream,
                       slots, codebook, (float4*)out);
}

// Round 5
// 186.504 us; speedup vs baseline: 1.5885x; 1.5885x over previous
//
#include <hip/hip_runtime.h>
#include <stdint.h>

// Problem constants
#define CC    1024
#define EE    320
#define KN    640         // G*E
#define DD    256
#define MTOT  16384       // B*T
#define WK2   2048        // B2 row stride (shorts): [hi(0:1024) | lo(1024:2048)]

typedef __attribute__((ext_vector_type(8))) short short8;
typedef __attribute__((ext_vector_type(4))) float f32x4;

__device__ __forceinline__ unsigned int f32_orderable(float x) {
    unsigned int b = __float_as_uint(x);
    return (b & 0x80000000u) ? ~b : (b | 0x80000000u);
}

__device__ __forceinline__ unsigned short bf16_rne(float x) {
    unsigned int u = __float_as_uint(x);
    return (unsigned short)((u + 0x7FFFu + ((u >> 16) & 1u)) >> 16);
}

// 8 fp32 -> bf16 hi (round-half-up) + lo (bf16 of exact residual). err ~2^-17|x|.
__device__ __forceinline__ void cvt_hilo8(float4 a, float4 b, short8& hi, short8& lo) {
    float x[8] = {a.x, a.y, a.z, a.w, b.x, b.y, b.z, b.w};
#pragma unroll
    for (int j = 0; j < 8; j++) {
        unsigned int u  = __float_as_uint(x[j]);
        unsigned int v  = u + 0x8000u;
        float hif       = __uint_as_float(v & 0xFFFF0000u);
        float lof       = x[j] - hif;                 // exact in fp32
        unsigned int lu = __float_as_uint(lof) + 0x8000u;
        hi[j] = (short)(v >> 16);
        lo[j] = (short)(lu >> 16);
    }
}

__device__ __forceinline__ void gload_lds16(const void* g, void* l) {
    __builtin_amdgcn_global_load_lds(
        (const __attribute__((address_space(1))) unsigned int*)g,
        (__attribute__((address_space(3))) unsigned int*)l,
        16, 0, 0);
}

__global__ void init_slots_kernel(unsigned long long* __restrict__ slots) {
    if (threadIdx.x < 16) slots[threadIdx.x] = 0ull;
}

// ------------------- fused convert: X -> fragment-major A2F, W -> row-major B2, slot init ------
// A2F layout: for mb=m/16 (0..1023), kc=k/32 (0..31), part in {hi,lo}:
//   A2F[((mb*32+kc)*2+part)*512 + lane*8 + j] = part of X[mb*16+(lane&15)][kc*32+(lane>>4)*8+j]
// -> GEMM A-frag load is base + lane*16B: perfectly coalesced, matches 16x16x32 A-operand layout.
__global__ __launch_bounds__(256)
void convert_kernel(const float* __restrict__ X, const float* __restrict__ W,
                    unsigned short* __restrict__ A2F, unsigned short* __restrict__ B2,
                    unsigned long long* __restrict__ slots) {
    const int bid = blockIdx.x;
    if (bid < 8192) {                      // X part: 2,097,152 threads = 1024 mb x 32 kc x 64 lanes
        int gtid = bid * 256 + threadIdx.x;
        int lane = gtid & 63;
        int kc   = (gtid >> 6) & 31;
        int mb   = gtid >> 11;
        int row  = mb * 16 + (lane & 15);
        int col  = kc * 32 + ((lane >> 4) << 3);
        const float* p = X + (size_t)row * CC + col;
        float4 v0 = *(const float4*)p;
        float4 v1 = *(const float4*)(p + 4);
        short8 hi, lo;
        cvt_hilo8(v0, v1, hi, lo);
        size_t base = ((size_t)(mb * 32 + kc) * 2) * 512 + lane * 8;
        *(short8*)(A2F + base)       = hi;   // coalesced 1KB/wave
        *(short8*)(A2F + base + 512) = lo;
    } else {                               // W part: 640 blocks over 163,840 float4s
        if (bid == 8192 && threadIdx.x < 16) slots[threadIdx.x] = 0ull;
        int i4 = (bid - 8192) * 256 + threadIdx.x;
        int m = i4 >> 8;
        int k = (i4 & 255) * 4;
        float4 v = ((const float4*)W)[i4];
        ushort4 hi, lo;
        hi.x = bf16_rne(v.x); lo.x = bf16_rne(v.x - __uint_as_float((unsigned)hi.x << 16));
        hi.y = bf16_rne(v.y); lo.y = bf16_rne(v.y - __uint_as_float((unsigned)hi.y << 16));
        hi.z = bf16_rne(v.z); lo.z = bf16_rne(v.z - __uint_as_float((unsigned)hi.z << 16));
        hi.w = bf16_rne(v.w); lo.w = bf16_rne(v.w - __uint_as_float((unsigned)hi.w << 16));
        *(ushort4*)(B2 + (size_t)m * WK2 + k)        = hi;
        *(ushort4*)(B2 + (size_t)m * WK2 + 1024 + k) = lo;
    }
}

// ------------------- MFMA GEMM + fused argmax -------------------
// C = X*W^T via split-bf16 (ah*bh + al*bh + ah*bl).
// A: direct from fragment-major A2F (coalesced, no LDS, no cvt).
// B: swizzled LDS double-buffer via global_load_lds; one barrier per K=32 iter.
// A loads issued BEFORE B staging -> wait-for-A is vmcnt(4), B prefetch stays in flight.
__global__ __launch_bounds__(256, 3)
void gemm_argmax_mfma(const unsigned short* __restrict__ A2F,
                      const unsigned short* __restrict__ B2,
                      const float* __restrict__ bias,
                      unsigned long long* __restrict__ slots) {
    __shared__ unsigned short Bs[2][2][128 * 32];   // [buf][hi/lo], 64B/row, src-col-rotated
    __shared__ unsigned long long red[4];

    const int tid  = threadIdx.x;
    const int lane = tid & 63;
    const int wave = tid >> 6;

    // XCD swizzle: one XCD covers 16 m-tiles x all 5 n-tiles (n fastest) -> A2F L2 reuse.
    const int l   = blockIdx.x;        // 0..639
    const int xcd = l & 7;
    const int w   = l >> 3;
    const int mt  = xcd * 16 + w / 5;
    const int nt  = w % 5;
    const int m0 = mt * 128;
    const int n0 = nt * 128;

    const int wm = (wave >> 1) * 64;
    const int wn = (wave & 1) * 64;
    const int fr = lane & 15;
    const int q  = lane >> 4;

    // A fragment pointers: t-th 16-row tile, kc stride = 1024 shorts; lo at +512 shorts.
    const unsigned short* Ap[4];
#pragma unroll
    for (int t = 0; t < 4; t++)
        Ap[t] = A2F + ((size_t)(((m0 + wm) >> 4) + t) * 32) * 1024 + lane * 8;

    // B staging: per wave 2 chunks of 16 rows; source column slot rotated by (rowInTile>>1)
    // so fragment ds_read_b128s are bank-conflict-free (verified 0 conflicts in R4).
    int soff[2];
#pragma unroll
    for (int c = 0; c < 2; c++) {
        int rt   = wave * 32 + c * 16 + (lane >> 2);
        int slot = ((lane & 3) - (rt >> 1)) & 3;
        soff[c]  = (n0 + rt) * WK2 + slot * 8;
    }
    const int ldsb0 = (wave * 32) * 64;
    const int ldsb1 = (wave * 32 + 16) * 64;
    // fragment read offset (shorts): row (wn+fr), rotated column slot
    const int fbase = (wn + fr) * 32 + ((q + (fr >> 1)) & 3) * 8;

    f32x4 acc[4][4] = {};

    // prologue: stage B(buf0, k=0)
#pragma unroll
    for (int c = 0; c < 2; c++) {
        const unsigned short* sp = B2 + soff[c];
        int lb = c ? ldsb1 : ldsb0;
        gload_lds16(sp,        (char*)Bs[0][0] + lb);
        gload_lds16(sp + 1024, (char*)Bs[0][1] + lb);
    }

    for (int it = 0; it < 32; it++) {
        const int buf = it & 1;
        __syncthreads();            // B(buf) staged; prev iter's reads of buf^1 done

        // A loads first (coalesced dwordx4) -> their wait leaves B staging in flight
        short8 ah[4], al[4];
#pragma unroll
        for (int t = 0; t < 4; t++) {
            ah[t] = *(const short8*)(Ap[t]);
            al[t] = *(const short8*)(Ap[t] + 512);
            Ap[t] += 1024;
        }
        // stage next B tile into buf^1
        if (it < 31) {
            const int k1 = (it + 1) * 32;
#pragma unroll
            for (int c = 0; c < 2; c++) {
                const unsigned short* sp = B2 + soff[c] + k1;
                int lb = c ? ldsb1 : ldsb0;
                gload_lds16(sp,        (char*)Bs[buf ^ 1][0] + lb);
                gload_lds16(sp + 1024, (char*)Bs[buf ^ 1][1] + lb);
            }
        }
        // B fragments from LDS
        short8 bh[4], bl[4];
#pragma unroll
        for (int t = 0; t < 4; t++) {
            bh[t] = *(const short8*)&Bs[buf][0][fbase + t * 512];
            bl[t] = *(const short8*)&Bs[buf][1][fbase + t * 512];
        }
        // 48 MFMAs
#pragma unroll
        for (int ti = 0; ti < 4; ti++)
#pragma unroll
            for (int tj = 0; tj < 4; tj++)
                acc[ti][tj] = __builtin_amdgcn_mfma_f32_16x16x32_bf16(ah[ti], bh[tj], acc[ti][tj], 0, 0, 0);
#pragma unroll
        for (int ti = 0; ti < 4; ti++)
#pragma unroll
            for (int tj = 0; tj < 4; tj++)
                acc[ti][tj] = __builtin_amdgcn_mfma_f32_16x16x32_bf16(al[ti], bh[tj], acc[ti][tj], 0, 0, 0);
#pragma unroll
        for (int ti = 0; ti < 4; ti++)
#pragma unroll
            for (int tj = 0; tj < 4; tj++)
                acc[ti][tj] = __builtin_amdgcn_mfma_f32_16x16x32_bf16(ah[ti], bl[tj], acc[ti][tj], 0, 0, 0);
    }

    // ---- fused argmax epilogue ----
    // C/D layout (16x16x32): col = lane&15, row = (lane>>4)*4 + reg
    float bias4[4];
#pragma unroll
    for (int tj = 0; tj < 4; tj++) bias4[tj] = bias[n0 + wn + tj * 16 + (lane & 15)];

    unsigned long long best = 0ull;
#pragma unroll
    for (int ti = 0; ti < 4; ti++) {
#pragma unroll
        for (int r = 0; r < 4; r++) {
            int m  = m0 + wm + ti * 16 + (lane >> 4) * 4 + r;
            int tl = m & 1023;
#pragma unroll
            for (int tj = 0; tj < 4; tj++) {
                int n = n0 + wn + tj * 16 + (lane & 15);
                float v = acc[ti][tj][r] + bias4[tj];
                unsigned int c = (unsigned int)(tl * KN + n);
                unsigned long long p =
                    ((unsigned long long)f32_orderable(v) << 32) |
                    (unsigned long long)(~c);
                if (p > best) best = p;
            }
        }
    }
#pragma unroll
    for (int off = 32; off > 0; off >>= 1) {
        unsigned long long o = __shfl_down(best, off, 64);
        if (o > best) best = o;
    }
    if (lane == 0) red[wave] = best;
    __syncthreads();
    if (tid == 0) {
        unsigned long long b = red[0];
        for (int wv = 1; wv < 4; wv++) if (red[wv] > b) b = red[wv];
        atomicMax(slots + (m0 >> 10), b);
    }
}

// ------------------- fused zero + scatter (whole output, one launch) -------------------
__global__ __launch_bounds__(256)
void zs_kernel(const unsigned long long* __restrict__ slots,
               const float* __restrict__ codebook,
               float4* __restrict__ out4) {
    int i4 = blockIdx.x * 256 + threadIdx.x;       // 2,097,152 float4s
    int n  = i4 >> 7;                              // output row
    int c4 = i4 & 127;                             // float4 within 512-float row
    int b  = n >> 11;
    int h  = (n >> 10) & 1;
    unsigned long long p = slots[b * 2 + h];
    unsigned int c = ~(unsigned int)(p & 0xFFFFFFFFull);
    int tl = (int)(c / KN);
    int kg = (int)(c % KN);
    int nstar = b * 2048 + h * 1024 + tl;
    int g = kg / EE;
    float4 v = make_float4(0.f, 0.f, 0.f, 0.f);
    if (n == nstar && (c4 >> 6) == g)
        v = ((const float4*)codebook)[kg * 64 + (c4 & 63)];
    out4[i4] = v;
}

// ------------------- fp32 fallback (only if ws too small) -------------------
#define BM 128
#define BN 64
#define BK 32
#define LDA (BM + 4)
#define LDB (BN + 4)

__global__ __launch_bounds__(128)
void gemm_argmax_f32(const float* __restrict__ X, const float* __restrict__ W,
                     const float* __restrict__ bias,
                     unsigned long long* __restrict__ slots) {
    __shared__ float As[BK][LDA];
    __shared__ float Bs[BK][LDB];
    const int tid = threadIdx.x;
    const int m0 = blockIdx.y * BM;
    const int n0 = blockIdx.x * BN;
    const int tx = tid & 7, ty = tid >> 3;
    float acc[8][8];
#pragma unroll
    for (int i = 0; i < 8; i++)
#pragma unroll
        for (int j = 0; j < 8; j++) acc[i][j] = 0.0f;
    const int lm = tid >> 3, lk = (tid & 7) * 4;
    const float* Xb = X + (size_t)m0 * CC;
    const float* Wb = W + (size_t)n0 * CC;
    for (int k0 = 0; k0 < CC; k0 += BK) {
#pragma unroll
        for (int r = 0; r < 8; r++) {
            int m = r * 16 + lm;
            float4 v = *(const float4*)(Xb + (size_t)m * CC + k0 + lk);
            As[lk + 0][m] = v.x; As[lk + 1][m] = v.y; As[lk + 2][m] = v.z; As[lk + 3][m] = v.w;
        }
#pragma unroll
        for (int r = 0; r < 4; r++) {
            int m = r * 16 + lm;
            float4 v = *(const float4*)(Wb + (size_t)m * CC + k0 + lk);
            Bs[lk + 0][m] = v.x; Bs[lk + 1][m] = v.y; Bs[lk + 2][m] = v.z; Bs[lk + 3][m] = v.w;
        }
        __syncthreads();
#pragma unroll
        for (int kk = 0; kk < BK; kk++) {
            float4 a0 = *(const float4*)&As[kk][ty * 8];
            float4 a1 = *(const float4*)&As[kk][ty * 8 + 4];
            float4 b0 = *(const float4*)&Bs[kk][tx * 8];
            float4 b1 = *(const float4*)&Bs[kk][tx * 8 + 4];
            float a[8] = {a0.x, a0.y, a0.z, a0.w, a1.x, a1.y, a1.z, a1.w};
            float b[8] = {b0.x, b0.y, b0.z, b0.w, b1.x, b1.y, b1.z, b1.w};
#pragma unroll
            for (int i = 0; i < 8; i++)
#pragma unroll
                for (int j = 0; j < 8; j++) acc[i][j] = fmaf(a[i], b[j], acc[i][j]);
        }
        __syncthreads();
    }
    unsigned long long best = 0ull;
#pragma unroll
    for (int i = 0; i < 8; i++) {
        int mg = m0 + ty * 8 + i;
        int tl = mg & 1023;
#pragma unroll
        for (int j = 0; j < 8; j++) {
            int kg = n0 + tx * 8 + j;
            float v = acc[i][j] + bias[kg];
            unsigned int c = (unsigned int)(tl * KN + kg);
            unsigned long long p = ((unsigned long long)f32_orderable(v) << 32) |
                                   (unsigned long long)(~c);
            if (p > best) best = p;
        }
    }
#pragma unroll
    for (int off = 32; off > 0; off >>= 1) {
        unsigned long long o = __shfl_down(best, off, 64);
        if (o > best) best = o;
    }
    __shared__ unsigned long long red2[2];
    if ((tid & 63) == 0) red2[tid >> 6] = best;
    __syncthreads();
    if (tid == 0) {
        unsigned long long b0 = red2[0], b1 = red2[1];
        atomicMax(slots + (m0 >> 10), b0 > b1 ? b0 : b1);
    }
}

extern "C" void kernel_launch(void* const* d_in, const int* in_sizes, int n_in,
                              void* d_out, int out_size, void* d_ws, size_t ws_size,
                              hipStream_t stream) {
    const float* X        = (const float*)d_in[0];  // (8,2048,1024)
    const float* W        = (const float*)d_in[1];  // (640,1024)
    const float* bias     = (const float*)d_in[2];  // (640,)
    const float* codebook = (const float*)d_in[3];  // (640,256)
    float* out = (float*)d_out;                     // (8,2048,512) fp32

    unsigned long long* slots = (unsigned long long*)d_ws;
    const size_t A_off   = 256;
    const size_t A_bytes = (size_t)MTOT * CC * 2 * 2;   // 67,108,864 (hi+lo)
    const size_t B_off   = A_off + A_bytes;
    const size_t B_bytes = (size_t)KN * WK2 * 2;        // 2,621,440
    const size_t need = B_off + B_bytes;

    if (ws_size >= need) {
        unsigned short* A2F = (unsigned short*)((char*)d_ws + A_off);
        unsigned short* B2  = (unsigned short*)((char*)d_ws + B_off);
        hipLaunchKernelGGL(convert_kernel, dim3(8192 + 640), dim3(256), 0, stream,
                           X, W, A2F, B2, slots);
        hipLaunchKernelGGL(gemm_argmax_mfma, dim3(640), dim3(256), 0, stream,
                           A2F, B2, bias, slots);
    } else {
        hipLaunchKernelGGL(init_slots_kernel, dim3(1), dim3(64), 0, stream, slots);
        hipLaunchKernelGGL(gemm_argmax_f32, dim3(KN / BN, MTOT / BM), dim3(128), 0, stream,
                           X, W, bias, slots);
    }

    int n4 = out_size / 4;        // 2,097,152
    hipLaunchKernelGGL(zs_kernel, dim3(n4 / 256), dim3(256), 0, stream,
                       slots, codebook, (float4*)out);
}